// Round 1
// 1237.601 us; speedup vs baseline: 1.3141x; 1.3141x over previous
//
#include <hip/hip_runtime.h>

typedef _Float16 half_t;
typedef _Float16 half8 __attribute__((ext_vector_type(8)));
typedef _Float16 h2 __attribute__((ext_vector_type(2)));
typedef float float4v __attribute__((ext_vector_type(4)));
typedef unsigned uint4v __attribute__((ext_vector_type(4)));
typedef unsigned short us4 __attribute__((ext_vector_type(4)));

constexpr int NB = 64;    // batch
constexpr int NT = 50;    // steps
constexpr int NS = 256;   // state dim
constexpr int NA = 64;    // action dim
constexpr int NH = 256;   // hypernet hidden
constexpr int NG = 64;    // Chebyshev-Gauss nodes for ha(z) interpolation

constexpr float LO_SCALE = 2048.0f;
constexpr float LO_INV   = 1.0f / 2048.0f;
constexpr float ZC = 1.0f;   // node interval center: z = ctx + t/50 in [0, 1.98]
constexpr float ZR = 1.05f;  // half-width -> interval [-0.05, 2.05]
constexpr float PI_F = 3.14159265358979323846f;

#if defined(__has_builtin)
#if __has_builtin(__builtin_amdgcn_fdot2)
#define HAVE_FDOT2 1
#endif
#endif

__device__ __forceinline__ float fdot2f(h2 a, h2 b, float c) {
#ifdef HAVE_FDOT2
  return __builtin_amdgcn_fdot2(a, b, c, false);
#else
  return c + (float)a[0] * (float)b[0] + (float)a[1] * (float)b[1];
#endif
}

__device__ __forceinline__ h2 as_h2(unsigned u) {
  union { unsigned u; h2 v; } X; X.u = u; return X.v;
}
__device__ __forceinline__ void split_hl(float v, unsigned short& hs, unsigned short& ls) {
  half_t hi = (half_t)v;
  half_t lo = (half_t)((v - (float)hi) * LO_SCALE);
  union { half_t h; unsigned short s; } A;
  A.h = hi; hs = A.s;
  A.h = lo; ls = A.s;
}

// ---------------- small prep kernels ----------------

__global__ void k_zero(unsigned* __restrict__ p, int n) {
  int idx = blockIdx.x * 256 + threadIdx.x;
  if (idx < n) p[idx] = 0u;
}

// G^T[h][g] = tanh(z_g * W1a[h] + b1a[h])
__global__ void k_g(const float* __restrict__ W1a, const float* __restrict__ b1a,
                    float* __restrict__ Gt) {
  int g = blockIdx.x, h = threadIdx.x;
  float th = PI_F * (float)(2 * g + 1) / (float)(2 * NG);
  float zg = ZC + ZR * cosf(th);
  Gt[h * NG + g] = tanhf(zg * W1a[h] + b1a[h]);
}

// HB[t][b][h] = tanh(z * W1b[h] + b1b[h])
__global__ void k_hb(const float* __restrict__ ctx, const float* __restrict__ W1b,
                     const float* __restrict__ b1b, float* __restrict__ HB) {
  int tb = blockIdx.x;
  int t = tb / NB, b = tb % NB;
  int h = threadIdx.x;
  float z = ctx[b] + (float)t / 50.0f;
  HB[(size_t)tb * NH + h] = tanhf(z * W1b[h] + b1b[h]);
}

// V[t][b][i] = b2b-row(i) . u[t,b]
__global__ void k_v(const float* __restrict__ b2b, const float* __restrict__ us,
                    float* __restrict__ V) {
  int tb = blockIdx.x;
  int t = tb / NB, b = tb % NB;
  int i = threadIdx.x;
  __shared__ float ush[NA];
  if (i < NA) ush[i] = us[((size_t)b * NT + t) * NA + i];
  __syncthreads();
  const float* row = b2b + (size_t)i * NA;
  float s = 0.f;
#pragma unroll 8
  for (int j = 0; j < NA; ++j) s += row[j] * ush[j];
  V[(size_t)tb * NS + i] = s;
}

// U hi/lo halves, [t][b][j]
__global__ void k_u(const float* __restrict__ us, half_t* __restrict__ Uh,
                    half_t* __restrict__ Ul) {
  int t = blockIdx.x, tid = threadIdx.x;
  for (int r = 0; r < 16; ++r) {
    int idx = r * 256 + tid;
    int b = idx >> 6, j = idx & 63;
    float u = us[((size_t)b * NT + t) * NA + j];
    half_t hi = (half_t)u;
    Uh[((size_t)t * NB + b) * NA + j] = hi;
    Ul[((size_t)t * NB + b) * NA + j] = (half_t)((u - (float)hi) * LO_SCALE);
  }
}

// barycentric Lagrange weights L_g(z_tb), split hi/lo, [tb][g]
__global__ void k_lag(const float* __restrict__ ctx,
                      unsigned short* __restrict__ Lph,
                      unsigned short* __restrict__ Lpl) {
  int idx = blockIdx.x * 256 + threadIdx.x;
  if (idx >= NT * NB) return;
  int t = idx >> 6, b = idx & 63;
  float z = ctx[b] + (float)t / 50.0f;
  float q[NG];
  float den = 0.f;
  int hit = -1;
#pragma unroll
  for (int g = 0; g < NG; ++g) {
    float th = PI_F * (float)(2 * g + 1) / (float)(2 * NG);
    float zg = ZC + ZR * cosf(th);
    float d = z - zg;
    if (fabsf(d) < 1e-7f) hit = g;
    float lam = ((g & 1) ? -1.f : 1.f) * sinf(th);
    float qq = lam / d;
    q[g] = qq;
    den += qq;
  }
  float rden = 1.f / den;
#pragma unroll
  for (int g = 0; g < NG; ++g) {
    float L = (hit >= 0) ? ((g == hit) ? 1.f : 0.f) : q[g] * rden;
    unsigned short hs, ls;
    split_hl(L, hs, ls);
    Lph[(size_t)idx * NG + g] = hs;
    Lpl[(size_t)idx * NG + g] = ls;
  }
}

// MG[g][m] = sum_h Gt[h][g] * W2a[h][m]; stored transposed as [m][g] hi/lo halves
__launch_bounds__(256)
__global__ void k_mg(const float* __restrict__ W2a, const float* __restrict__ Gt,
                     unsigned short* __restrict__ MGh, unsigned short* __restrict__ MGl) {
  __shared__ unsigned short th_[256 * 66];
  __shared__ unsigned short tl_[256 * 66];
  const int tid = threadIdx.x;
  const size_t m = (size_t)blockIdx.x * 256 + tid;
  float acc[NG];
#pragma unroll
  for (int g = 0; g < NG; ++g) acc[g] = 0.f;
  for (int h = 0; h < NH; ++h) {
    float w = W2a[(size_t)h * (NS * NS) + m];
    const float* gr = Gt + h * NG;   // uniform -> scalar loads
#pragma unroll
    for (int g = 0; g < NG; ++g) acc[g] += gr[g] * w;
  }
#pragma unroll
  for (int g = 0; g < NG; ++g) {
    unsigned short hs, ls;
    split_hl(acc[g], hs, ls);
    th_[tid * 66 + g] = hs;
    tl_[tid * 66 + g] = ls;
  }
  __syncthreads();
  const size_t base = (size_t)blockIdx.x * (256 * NG);
#pragma unroll 4
  for (int it = 0; it < 16; ++it) {
    int idx4 = it * 1024 + tid * 4;
    int ml = idx4 >> 6, g = idx4 & 63;
    us4 hv, lv;
#pragma unroll
    for (int k = 0; k < 4; ++k) {
      hv[k] = th_[ml * 66 + g + k];
      lv[k] = tl_[ml * 66 + g + k];
    }
    *(us4*)(MGh + base + idx4) = hv;
    *(us4*)(MGl + base + idx4) = lv;
  }
}

// x0 -> packed hi|lo state
__global__ void k_x0(const float* __restrict__ x0, unsigned* __restrict__ Xst) {
  int idx = blockIdx.x * 256 + threadIdx.x;
  float x = x0[idx];
  half_t hi = (half_t)x;
  half_t lo = (half_t)((x - (float)hi) * LO_SCALE);
  union { half_t h[2]; unsigned u; } P;
  P.h[0] = hi; P.h[1] = lo;
  Xst[idx] = P.u;
}

// Bu hypernet part -> Y[t][i][b] (atomics); x-independent, fully parallel.
__launch_bounds__(256)
__global__ void k_bu(const float* __restrict__ W2b, const half_t* __restrict__ Uh,
                     const half_t* __restrict__ Ul, const float* __restrict__ HB,
                     float* __restrict__ Y) {
  const int tid = threadIdx.x;
  const int i  = blockIdx.x >> 1;
  const int hh = blockIdx.x & 1;
  const int lane = tid & 63, wv = tid >> 6;
  const int l15 = lane & 15, quad = lane >> 4;

  half8 auh[2][2], aul[2][2];   // [kb][mt], converted once from f32
#pragma unroll
  for (int kb = 0; kb < 2; ++kb) {
    const int jo = kb * 32 + quad * 8;
#pragma unroll
    for (int mt = 0; mt < 2; ++mt) {
      const int hg = hh * 128 + (wv * 2 + mt) * 16 + l15;
      const float* src = W2b + (size_t)hg * (NS * NA) + (size_t)i * NA + jo;
      float4v w0 = *(const float4v*)(src);
      float4v w1 = *(const float4v*)(src + 4);
      half8 oh, ol;
#pragma unroll
      for (int r = 0; r < 4; ++r) {
        half_t h0 = (half_t)w0[r];
        half_t h1 = (half_t)w1[r];
        oh[r] = h0; oh[r + 4] = h1;
        ol[r]     = (half_t)((w0[r] - (float)h0) * LO_SCALE);
        ol[r + 4] = (half_t)((w1[r] - (float)h1) * LO_SCALE);
      }
      auh[kb][mt] = oh; aul[kb][mt] = ol;
    }
  }
  for (int t = 0; t < NT; ++t) {
    float4v aU[2][4], aUc[2][4];
#pragma unroll
    for (int mt = 0; mt < 2; ++mt)
#pragma unroll
      for (int nt = 0; nt < 4; ++nt) {
        aU[mt][nt] = (float4v){0.f, 0.f, 0.f, 0.f};
        aUc[mt][nt] = (float4v){0.f, 0.f, 0.f, 0.f};
      }
#pragma unroll
    for (int kb = 0; kb < 2; ++kb) {
      const int jo = kb * 32 + quad * 8;
      half8 buh[4], bul[4];
#pragma unroll
      for (int nt = 0; nt < 4; ++nt) {
        int b = nt * 16 + l15;
        buh[nt] = *(const half8*)(Uh + ((size_t)t * NB + b) * NA + jo);
        bul[nt] = *(const half8*)(Ul + ((size_t)t * NB + b) * NA + jo);
      }
#pragma unroll
      for (int mt = 0; mt < 2; ++mt)
#pragma unroll
        for (int nt = 0; nt < 4; ++nt) {
          aU[mt][nt]  = __builtin_amdgcn_mfma_f32_16x16x32_f16(auh[kb][mt], buh[nt], aU[mt][nt], 0, 0, 0);
          aUc[mt][nt] = __builtin_amdgcn_mfma_f32_16x16x32_f16(auh[kb][mt], bul[nt], aUc[mt][nt], 0, 0, 0);
          aUc[mt][nt] = __builtin_amdgcn_mfma_f32_16x16x32_f16(aul[kb][mt], buh[nt], aUc[mt][nt], 0, 0, 0);
        }
    }
    float part[4] = {0.f, 0.f, 0.f, 0.f};
#pragma unroll
    for (int mt = 0; mt < 2; ++mt) {
      int hg = hh * 128 + (wv * 2 + mt) * 16 + quad * 4;
#pragma unroll
      for (int nt = 0; nt < 4; ++nt) {
        int b = nt * 16 + l15;
        float4v hb4 = *(const float4v*)(HB + ((size_t)t * NB + b) * NH + hg);
#pragma unroll
        for (int r = 0; r < 4; ++r)
          part[nt] += hb4[r] * (aU[mt][nt][r] + aUc[mt][nt][r] * LO_INV);
      }
    }
#pragma unroll
    for (int nt = 0; nt < 4; ++nt) {
      part[nt] += __shfl_xor(part[nt], 16);
      part[nt] += __shfl_xor(part[nt], 32);
    }
    if (quad == 0) {
      float* Yrow = Y + ((size_t)t * NS + i) * NB;
#pragma unroll
      for (int nt = 0; nt < 4; ++nt) atomicAdd(&Yrow[nt * 16 + l15], part[nt]);
    }
  }
}

// V[t][b][i] += Y[t][i][b] (LDS transpose per t)
__global__ void k_fold(const float* __restrict__ Y, float* __restrict__ V) {
  __shared__ float s[256 * 65];
  int t = blockIdx.x, tid = threadIdx.x;
  for (int it = 0; it < 64; ++it) {
    int idx = it * 256 + tid;                   // i = idx>>6, b = idx&63
    s[(idx >> 6) * 65 + (idx & 63)] = Y[(size_t)t * (NS * NB) + idx];
  }
  __syncthreads();
  for (int it = 0; it < 64; ++it) {
    int idx = it * 256 + tid;                   // b = idx>>8, i = idx&255
    int b = idx >> 8, ii = idx & 255;
    V[((size_t)t * NB + b) * NS + ii] += s[ii * 65 + b];
  }
}

// ---------------- A-materialization GEMM (per t-chunk) ----------------
// A[tb][m] = sum_g L[tb][g] * MG[g][m] + b2a[m], hi/lo f16, M=64*tn, K=64, N=65536
__launch_bounds__(256, 2)
__global__ void k_pre(const unsigned short* __restrict__ Lph,
                      const unsigned short* __restrict__ Lpl,
                      const unsigned short* __restrict__ MGh,
                      const unsigned short* __restrict__ MGl,
                      const float* __restrict__ b2a,
                      unsigned short* __restrict__ Ahi,
                      unsigned short* __restrict__ Alo,
                      int t0) {
  __shared__ unsigned short sh[4][16 * 256];
  __shared__ unsigned short sl[4][16 * 256];
  const int tid = threadIdx.x;
  const int wv = tid >> 6, lane = tid & 63;
  const int l15 = lane & 15, quad = lane >> 4;
  const int cb = (blockIdx.x & 255) << 8;   // column (m) base
  const int rt = blockIdx.x >> 8;           // row tile (64 chunk-rows)
  const int r0 = rt * 64 + wv * 16;         // wave's chunk-row base

  half8 Lh[2], Ll[2];
  {
    const size_t lb = ((size_t)t0 * NB + r0 + l15) * NG + quad * 8;
#pragma unroll
    for (int kk = 0; kk < 2; ++kk) {
      Lh[kk] = *(const half8*)(Lph + lb + kk * 32);
      Ll[kk] = *(const half8*)(Lpl + lb + kk * 32);
    }
  }
  float4v accA[16], accC[16];
#pragma unroll
  for (int cf = 0; cf < 16; ++cf) {
    accA[cf] = (float4v){0.f, 0.f, 0.f, 0.f};
    accC[cf] = (float4v){0.f, 0.f, 0.f, 0.f};
  }
#pragma unroll
  for (int cf = 0; cf < 16; ++cf) {
    const size_t mb = (size_t)(cb + cf * 16 + l15) * NG + quad * 8;
#pragma unroll
    for (int kk = 0; kk < 2; ++kk) {
      half8 Bh = *(const half8*)(MGh + mb + kk * 32);
      half8 Bl = *(const half8*)(MGl + mb + kk * 32);
      accA[cf] = __builtin_amdgcn_mfma_f32_16x16x32_f16(Lh[kk], Bh, accA[cf], 0, 0, 0);
      accC[cf] = __builtin_amdgcn_mfma_f32_16x16x32_f16(Lh[kk], Bl, accC[cf], 0, 0, 0);
      accC[cf] = __builtin_amdgcn_mfma_f32_16x16x32_f16(Ll[kk], Bh, accC[cf], 0, 0, 0);
    }
  }
#pragma unroll
  for (int cf = 0; cf < 16; ++cf) {
    const int mloc = cf * 16 + l15;
    const float b2 = b2a[cb + mloc];
#pragma unroll
    for (int r = 0; r < 4; ++r) {
      float v = accA[cf][r] + accC[cf][r] * LO_INV + b2;
      unsigned short hs, ls;
      split_hl(v, hs, ls);
      const int row = quad * 4 + r;
      sh[wv][row * 256 + mloc] = hs;
      sl[wv][row * 256 + mloc] = ls;
    }
  }
  __syncthreads();
#pragma unroll
  for (int it = 0; it < 16; ++it) {
    us4 hv = *(const us4*)(&sh[wv][it * 256 + lane * 4]);
    us4 lv = *(const us4*)(&sl[wv][it * 256 + lane * 4]);
    const size_t gb = (size_t)(r0 + it) * (NS * NS) + cb + lane * 4;
    *(us4*)(Ahi + gb) = hv;
    *(us4*)(Alo + gb) = lv;
  }
}

// ---------------- rollout: 64 independent per-batch chains ----------------
// one wg (16 waves) per b; lane covers 4 i-rows x 16 j; x double-buffered in LDS.
__launch_bounds__(1024, 4)
__global__ void k_roll(const unsigned short* __restrict__ Ahi,
                       const unsigned short* __restrict__ Alo,
                       const float* __restrict__ V,
                       unsigned* __restrict__ Xst,
                       float* __restrict__ out,
                       int t0, int tn) {
  __shared__ unsigned short xh[2][256], xl[2][256];
  const int b = blockIdx.x, tid = threadIdx.x;
  const int wv = tid >> 6, lane = tid & 63;
  const int jg = lane & 15, ir = lane >> 4;
  const int i0 = wv * 16 + ir * 4;
  if (tid < 256) {
    unsigned p = Xst[b * 256 + tid];
    xh[0][tid] = (unsigned short)(p & 0xffffu);
    xl[0][tid] = (unsigned short)(p >> 16);
  }
  __syncthreads();
  int cur = 0;
  for (int tt = 0; tt < tn; ++tt) {
    const int t = t0 + tt;
    const size_t rb = ((size_t)tt * NB + b) * (NS * NS);
    uint4v ah[8], al[8];
#pragma unroll
    for (int i = 0; i < 4; ++i) {
      const size_t ro = rb + (size_t)(i0 + i) * NS + jg * 16;
      ah[i * 2 + 0] = *(const uint4v*)(Ahi + ro);
      ah[i * 2 + 1] = *(const uint4v*)(Ahi + ro + 8);
      al[i * 2 + 0] = *(const uint4v*)(Alo + ro);
      al[i * 2 + 1] = *(const uint4v*)(Alo + ro + 8);
    }
    uint4v xhv[2], xlv[2];
    xhv[0] = *(const uint4v*)(&xh[cur][jg * 16]);
    xhv[1] = *(const uint4v*)(&xh[cur][jg * 16 + 8]);
    xlv[0] = *(const uint4v*)(&xl[cur][jg * 16]);
    xlv[1] = *(const uint4v*)(&xl[cur][jg * 16 + 8]);
    float d1[4] = {0.f, 0.f, 0.f, 0.f}, d2[4] = {0.f, 0.f, 0.f, 0.f};
#pragma unroll
    for (int i = 0; i < 4; ++i)
#pragma unroll
      for (int q = 0; q < 2; ++q)
#pragma unroll
        for (int p = 0; p < 4; ++p) {
          h2 a2h = as_h2(ah[i * 2 + q][p]);
          h2 a2l = as_h2(al[i * 2 + q][p]);
          h2 x2h = as_h2(xhv[q][p]);
          h2 x2l = as_h2(xlv[q][p]);
          d1[i] = fdot2f(a2h, x2h, d1[i]);
          d2[i] = fdot2f(a2h, x2l, d2[i]);
          d2[i] = fdot2f(a2l, x2h, d2[i]);
        }
    float dt[4];
#pragma unroll
    for (int i = 0; i < 4; ++i) dt[i] = d1[i] + d2[i] * LO_INV;
#pragma unroll
    for (int s = 1; s < 16; s <<= 1)
#pragma unroll
      for (int i = 0; i < 4; ++i) dt[i] += __shfl_xor(dt[i], s);
    if (jg == 0) {
      float4v vv = *(const float4v*)(V + ((size_t)t * NB + b) * NS + i0);
      float4v xn;
#pragma unroll
      for (int i = 0; i < 4; ++i) xn[i] = dt[i] + vv[i];
      *(float4v*)(out + ((size_t)b * NT + t) * NS + i0) = xn;
      us4 nh, nl;
#pragma unroll
      for (int i = 0; i < 4; ++i) {
        unsigned short hs, ls;
        split_hl(xn[i], hs, ls);
        nh[i] = hs; nl[i] = ls;
      }
      *(us4*)(&xh[cur ^ 1][i0]) = nh;
      *(us4*)(&xl[cur ^ 1][i0]) = nl;
    }
    __syncthreads();
    cur ^= 1;
  }
  if (tid < 256) {
    unsigned p = (unsigned)xh[cur][tid] | ((unsigned)xl[cur][tid] << 16);
    Xst[b * 256 + tid] = p;
  }
}

// ---------------- launch ----------------

extern "C" void kernel_launch(void* const* d_in, const int* in_sizes, int n_in,
                              void* d_out, int out_size, void* d_ws, size_t ws_size,
                              hipStream_t stream) {
  const float* x0  = (const float*)d_in[0];
  const float* ctx = (const float*)d_in[1];
  const float* us  = (const float*)d_in[2];
  const float* W1a = (const float*)d_in[3];
  const float* b1a = (const float*)d_in[4];
  const float* W2a = (const float*)d_in[5];
  const float* b2a = (const float*)d_in[6];
  const float* W1b = (const float*)d_in[7];
  const float* b1b = (const float*)d_in[8];
  const float* W2b = (const float*)d_in[9];
  const float* b2b = (const float*)d_in[10];
  float* out = (float*)d_out;

  const size_t szMG1 = (size_t)NS * NS * NG * 2;   //  8,388,608 each
  const size_t szLp1 = (size_t)NT * NB * NG * 2;   //    409,600 each
  const size_t szGt  = (size_t)NH * NG * 4;        //     65,536
  const size_t szHB  = (size_t)NT * NB * NH * 4;   //  3,276,800
  const size_t szV   = (size_t)NT * NB * NS * 4;   //  3,276,800
  const size_t szY   = szV;
  const size_t szU1  = (size_t)NT * NB * NA * 2;   //    409,600 each
  const size_t szXst = (size_t)NB * NS * 4;        //     65,536
  const size_t fixed = 2 * szMG1 + 2 * szLp1 + szGt + szHB + szV + szY + 2 * szU1 + szXst;
  const size_t per_t = (size_t)NB * NS * NS * 2 * 2;   // 16,777,216 per step (hi+lo)

  size_t avail = (ws_size > fixed) ? (ws_size - fixed) : 0;
  int Tc = (int)(avail / per_t);
  if (Tc > 13) Tc = 13;   // cap: 4 chunks; chunk (<=218 MB) can stay MALL-resident
  if (Tc < 1) Tc = 1;

  char* p = (char*)d_ws;
  unsigned short* Ahi = (unsigned short*)p; p += (size_t)Tc * NB * NS * NS * 2;
  unsigned short* Alo = (unsigned short*)p; p += (size_t)Tc * NB * NS * NS * 2;
  unsigned short* MGh = (unsigned short*)p; p += szMG1;
  unsigned short* MGl = (unsigned short*)p; p += szMG1;
  unsigned short* Lph = (unsigned short*)p; p += szLp1;
  unsigned short* Lpl = (unsigned short*)p; p += szLp1;
  float* Gt  = (float*)p; p += szGt;
  float* HBg = (float*)p; p += szHB;
  float* Vg  = (float*)p; p += szV;
  float* Yg  = (float*)p; p += szY;
  half_t* Uh = (half_t*)p; p += szU1;
  half_t* Ul = (half_t*)p; p += szU1;
  unsigned* Xst = (unsigned*)p;

  {
    int nwords = (int)(szY / 4);
    k_zero<<<(nwords + 255) / 256, 256, 0, stream>>>((unsigned*)Yg, nwords);
  }
  k_g<<<NG, NH, 0, stream>>>(W1a, b1a, Gt);
  k_hb<<<NT * NB, NH, 0, stream>>>(ctx, W1b, b1b, HBg);
  k_v<<<NT * NB, NS, 0, stream>>>(b2b, us, Vg);
  k_u<<<NT, 256, 0, stream>>>(us, Uh, Ul);
  k_lag<<<(NT * NB + 255) / 256, 256, 0, stream>>>(ctx, Lph, Lpl);
  k_mg<<<NS * NS / 256, 256, 0, stream>>>(W2a, Gt, MGh, MGl);
  k_x0<<<NB, 256, 0, stream>>>(x0, Xst);
  k_bu<<<2 * NS, 256, 0, stream>>>(W2b, Uh, Ul, HBg, Yg);
  k_fold<<<NT, 256, 0, stream>>>(Yg, Vg);

  for (int t0 = 0; t0 < NT; t0 += Tc) {
    int tn = (NT - t0 < Tc) ? (NT - t0) : Tc;
    k_pre<<<tn * 256, 256, 0, stream>>>(Lph, Lpl, MGh, MGl, b2a, Ahi, Alo, t0);
    k_roll<<<NB, 1024, 0, stream>>>(Ahi, Alo, Vg, Xst, out, t0, tn);
  }
}

// Round 2
// 1136.993 us; speedup vs baseline: 1.4304x; 1.0885x over previous
//
#include <hip/hip_runtime.h>

typedef _Float16 half_t;
typedef _Float16 half8 __attribute__((ext_vector_type(8)));
typedef _Float16 h2 __attribute__((ext_vector_type(2)));
typedef float float4v __attribute__((ext_vector_type(4)));
typedef unsigned uint4v __attribute__((ext_vector_type(4)));
typedef unsigned short us4 __attribute__((ext_vector_type(4)));
typedef unsigned short us8 __attribute__((ext_vector_type(8)));

constexpr int NB = 64;    // batch
constexpr int NT = 50;    // steps
constexpr int NS = 256;   // state dim
constexpr int NA = 64;    // action dim
constexpr int NH = 256;   // hypernet hidden
constexpr int NG = 64;    // Chebyshev-Gauss nodes for tanh(z*w+b) interpolation

constexpr float LO_SCALE = 2048.0f;
constexpr float LO_INV   = 1.0f / 2048.0f;
constexpr float ZC = 1.0f;   // z = ctx + t/50 in [0, 1.98]
constexpr float ZR = 1.05f;  // interval [-0.05, 2.05]
constexpr float PI_F = 3.14159265358979323846f;

#if defined(__has_builtin)
#if __has_builtin(__builtin_amdgcn_fdot2)
#define HAVE_FDOT2 1
#endif
#endif

__device__ __forceinline__ float fdot2f(h2 a, h2 b, float c) {
#ifdef HAVE_FDOT2
  return __builtin_amdgcn_fdot2(a, b, c, false);
#else
  return c + (float)a[0] * (float)b[0] + (float)a[1] * (float)b[1];
#endif
}

__device__ __forceinline__ h2 as_h2(unsigned u) {
  union { unsigned u; h2 v; } X; X.u = u; return X.v;
}
__device__ __forceinline__ void split_hl(float v, unsigned short& hs, unsigned short& ls) {
  half_t hi = (half_t)v;
  half_t lo = (half_t)((v - (float)hi) * LO_SCALE);
  union { half_t h; unsigned short s; } A;
  A.h = hi; hs = A.s;
  A.h = lo; ls = A.s;
}

// ---------------- prep kernels ----------------

// Gt[h][g] = tanh(z_g*W1a[h]+b1a[h]); Gbt likewise for b-net
__global__ void k_g(const float* __restrict__ W1a, const float* __restrict__ b1a,
                    const float* __restrict__ W1b, const float* __restrict__ b1b,
                    float* __restrict__ Gt, float* __restrict__ Gbt) {
  int g = blockIdx.x, h = threadIdx.x;
  float th = PI_F * (float)(2 * g + 1) / (float)(2 * NG);
  float zg = ZC + ZR * cosf(th);
  Gt[h * NG + g]  = tanhf(zg * W1a[h] + b1a[h]);
  Gbt[h * NG + g] = tanhf(zg * W1b[h] + b1b[h]);
}

// barycentric Lagrange weights L_g(z_tb): f32 + hi/lo f16, [tb][g]
__global__ void k_lag(const float* __restrict__ ctx, float* __restrict__ Lf,
                      unsigned short* __restrict__ Lph,
                      unsigned short* __restrict__ Lpl) {
  int idx = blockIdx.x * 256 + threadIdx.x;
  if (idx >= NT * NB) return;
  int t = idx >> 6, b = idx & 63;
  float z = ctx[b] + (float)t / 50.0f;
  float q[NG];
  float den = 0.f;
  int hit = -1;
#pragma unroll
  for (int g = 0; g < NG; ++g) {
    float th = PI_F * (float)(2 * g + 1) / (float)(2 * NG);
    float zg = ZC + ZR * cosf(th);
    float d = z - zg;
    if (fabsf(d) < 1e-7f) hit = g;
    float lam = ((g & 1) ? -1.f : 1.f) * sinf(th);
    float qq = lam / d;
    q[g] = qq;
    den += qq;
  }
  float rden = 1.f / den;
#pragma unroll
  for (int g = 0; g < NG; ++g) {
    float L = (hit >= 0) ? ((g == hit) ? 1.f : 0.f) : q[g] * rden;
    Lf[(size_t)idx * NG + g] = L;
    unsigned short hs, ls;
    split_hl(L, hs, ls);
    Lph[(size_t)idx * NG + g] = hs;
    Lpl[(size_t)idx * NG + g] = ls;
  }
}

// V[t][b][i] = b2b-row(i) . u[t,b]
__global__ void k_v(const float* __restrict__ b2b, const float* __restrict__ us,
                    float* __restrict__ V) {
  int tb = blockIdx.x;
  int t = tb / NB, b = tb % NB;
  int i = threadIdx.x;
  __shared__ float ush[NA];
  if (i < NA) ush[i] = us[((size_t)b * NT + t) * NA + i];
  __syncthreads();
  const float* row = b2b + (size_t)i * NA;
  float s = 0.f;
#pragma unroll 8
  for (int j = 0; j < NA; ++j) s += row[j] * ush[j];
  V[(size_t)tb * NS + i] = s;
}

// MG[m][g] = sum_h Gt[h][g]*W2a[h][m], hi/lo f16 (m = i*NS + j, 65536 of them)
__launch_bounds__(256)
__global__ void k_mg(const float* __restrict__ W2a, const float* __restrict__ Gt,
                     unsigned short* __restrict__ MGh, unsigned short* __restrict__ MGl) {
  __shared__ unsigned short th_[256 * 66];
  __shared__ unsigned short tl_[256 * 66];
  const int tid = threadIdx.x;
  const size_t m = (size_t)blockIdx.x * 256 + tid;
  float acc[NG];
#pragma unroll
  for (int g = 0; g < NG; ++g) acc[g] = 0.f;
  for (int h = 0; h < NH; ++h) {
    float w = W2a[(size_t)h * (NS * NS) + m];
    const float* gr = Gt + h * NG;   // uniform -> scalar loads
#pragma unroll
    for (int g = 0; g < NG; ++g) acc[g] += gr[g] * w;
  }
#pragma unroll
  for (int g = 0; g < NG; ++g) {
    unsigned short hs, ls;
    split_hl(acc[g], hs, ls);
    th_[tid * 66 + g] = hs;
    tl_[tid * 66 + g] = ls;
  }
  __syncthreads();
  const size_t base = (size_t)blockIdx.x * (256 * NG);
#pragma unroll 4
  for (int it = 0; it < 16; ++it) {
    int idx4 = it * 1024 + tid * 4;
    int ml = idx4 >> 6, g = idx4 & 63;
    us4 hv, lv;
#pragma unroll
    for (int k = 0; k < 4; ++k) {
      hv[k] = th_[ml * 66 + g + k];
      lv[k] = tl_[ml * 66 + g + k];
    }
    *(us4*)(MGh + base + idx4) = hv;
    *(us4*)(MGl + base + idx4) = lv;
  }
}

// MBT[i][g*64+j] = sum_h Gbt[h][g]*W2b[h][i*64+j], hi/lo f16
__launch_bounds__(256)
__global__ void k_mb(const float* __restrict__ W2b, const float* __restrict__ Gbt,
                     unsigned short* __restrict__ MBTh, unsigned short* __restrict__ MBTl) {
  __shared__ unsigned short sh_[256 * 66];
  __shared__ unsigned short sl_[256 * 66];
  const int tid = threadIdx.x;
  const int m = blockIdx.x * 256 + tid;          // m = i*64 + j, 16384 total
  float acc[NG];
#pragma unroll
  for (int g = 0; g < NG; ++g) acc[g] = 0.f;
  for (int h = 0; h < NH; ++h) {
    float w = W2b[(size_t)h * (NS * NA) + m];
    const float* gr = Gbt + h * NG;
#pragma unroll
    for (int g = 0; g < NG; ++g) acc[g] += gr[g] * w;
  }
#pragma unroll
  for (int g = 0; g < NG; ++g) {
    unsigned short hs, ls;
    split_hl(acc[g], hs, ls);
    sh_[tid * 66 + g] = hs;
    sl_[tid * 66 + g] = ls;
  }
  __syncthreads();
  const int i0 = blockIdx.x * 4;                 // block covers 4 i-rows
  for (int it = 0; it < 64; ++it) {
    int flat = it * 256 + tid;                   // ii*4096 + K
    int ii = flat >> 12, K = flat & 4095;
    int g = K >> 6, j = K & 63;
    MBTh[(size_t)(i0 + ii) * 4096 + K] = sh_[(ii * 64 + j) * 66 + g];
    MBTl[(size_t)(i0 + ii) * 4096 + K] = sl_[(ii * 64 + j) * 66 + g];
  }
}

// Up[tb][g*64+j] = L_g[tb]*u[tb][j], hi/lo f16
__global__ void k_up(const float* __restrict__ Lf, const float* __restrict__ usin,
                     unsigned short* __restrict__ Uph, unsigned short* __restrict__ Upl) {
  int tb = blockIdx.x, tid = threadIdx.x;
  int t = tb >> 6, b = tb & 63;
  __shared__ float Ls[64], uu[64];
  if (tid < 64) Ls[tid] = Lf[(size_t)tb * NG + tid];
  else if (tid < 128) uu[tid - 64] = usin[((size_t)b * NT + t) * NA + (tid - 64)];
  __syncthreads();
  float Lg = Ls[tid >> 2];
  int j0 = (tid & 3) * 16;
  us8 hv0, hv1, lv0, lv1;
#pragma unroll
  for (int k = 0; k < 8; ++k) {
    unsigned short hs, ls;
    split_hl(Lg * uu[j0 + k], hs, ls);
    hv0[k] = hs; lv0[k] = ls;
  }
#pragma unroll
  for (int k = 0; k < 8; ++k) {
    unsigned short hs, ls;
    split_hl(Lg * uu[j0 + 8 + k], hs, ls);
    hv1[k] = hs; lv1[k] = ls;
  }
  size_t ob = (size_t)tb * 4096 + tid * 16;
  *(us8*)(Uph + ob) = hv0; *(us8*)(Uph + ob + 8) = hv1;
  *(us8*)(Upl + ob) = lv0; *(us8*)(Upl + ob + 8) = lv1;
}

// x0 -> packed hi|lo state
__global__ void k_x0(const float* __restrict__ x0, unsigned* __restrict__ Xst) {
  int idx = blockIdx.x * 256 + threadIdx.x;
  float x = x0[idx];
  half_t hi = (half_t)x;
  half_t lo = (half_t)((x - (float)hi) * LO_SCALE);
  union { half_t h[2]; unsigned u; } P;
  P.h[0] = hi; P.h[1] = lo;
  Xst[idx] = P.u;
}

// Bu GEMM: V[tb][i] += sum_K Up[tb][K]*MBT[i][K]; M=3200, N=256, K=4096, Ksplit=4
__launch_bounds__(256, 2)
__global__ void k_bu2(const unsigned short* __restrict__ Uph,
                      const unsigned short* __restrict__ Upl,
                      const unsigned short* __restrict__ MBTh,
                      const unsigned short* __restrict__ MBTl,
                      float* __restrict__ V) {
  const int tid = threadIdx.x;
  const int wv = tid >> 6, lane = tid & 63;
  const int l15 = lane & 15, quad = lane >> 4;
  const int mt = blockIdx.x >> 2, ks = blockIdx.x & 3;
  const int r0 = mt * 64 + wv * 16;
  const int kb0 = ks * 1024;
  float4v accA[16], accC[16];
#pragma unroll
  for (int cf = 0; cf < 16; ++cf) {
    accA[cf] = (float4v){0.f, 0.f, 0.f, 0.f};
    accC[cf] = (float4v){0.f, 0.f, 0.f, 0.f};
  }
#pragma unroll
  for (int kt = 0; kt < 4; ++kt) {
    half8 ah[8], al[8];
    const size_t ab = (size_t)(r0 + l15) * 4096 + kb0 + kt * 256 + quad * 8;
#pragma unroll
    for (int k8 = 0; k8 < 8; ++k8) {
      ah[k8] = *(const half8*)(Uph + ab + k8 * 32);
      al[k8] = *(const half8*)(Upl + ab + k8 * 32);
    }
#pragma unroll
    for (int cf = 0; cf < 16; ++cf) {
      const size_t bb = (size_t)(cf * 16 + l15) * 4096 + kb0 + kt * 256 + quad * 8;
#pragma unroll
      for (int k8 = 0; k8 < 8; ++k8) {
        half8 bh = *(const half8*)(MBTh + bb + k8 * 32);
        half8 bl = *(const half8*)(MBTl + bb + k8 * 32);
        accA[cf] = __builtin_amdgcn_mfma_f32_16x16x32_f16(ah[k8], bh, accA[cf], 0, 0, 0);
        accC[cf] = __builtin_amdgcn_mfma_f32_16x16x32_f16(ah[k8], bl, accC[cf], 0, 0, 0);
        accC[cf] = __builtin_amdgcn_mfma_f32_16x16x32_f16(al[k8], bh, accC[cf], 0, 0, 0);
      }
    }
  }
#pragma unroll
  for (int cf = 0; cf < 16; ++cf) {
#pragma unroll
    for (int r = 0; r < 4; ++r) {
      int row = r0 + quad * 4 + r;
      atomicAdd(V + (size_t)row * NS + cf * 16 + l15,
                accA[cf][r] + accC[cf][r] * LO_INV);
    }
  }
}

// ---------------- fused pipeline kernel ----------------
// blocks [0, nroll): rollout chains for chunk (t0r, tnr) reading Arh/Arl.
// blocks [nroll, ...): A-materialization for chunk starting t0p writing Awh/Awl.
// No cross-block communication; disjoint buffers; chunk ordering via stream order.
__launch_bounds__(256, 2)
__global__ void k_pr(const unsigned short* Arh, const unsigned short* Arl,
                     unsigned short* Awh, unsigned short* Awl,
                     const unsigned short* __restrict__ Lph,
                     const unsigned short* __restrict__ Lpl,
                     const unsigned short* __restrict__ MGh,
                     const unsigned short* __restrict__ MGl,
                     const float* __restrict__ b2a, const float* __restrict__ V,
                     unsigned* __restrict__ Xst, float* __restrict__ out,
                     int nroll, int t0r, int tnr, int t0p) {
  __shared__ __align__(16) unsigned short xh[2][256];
  __shared__ __align__(16) unsigned short xl[2][256];
  const int tid = threadIdx.x;
  const int bid = blockIdx.x;

  if (bid < nroll) {
    // ===== rollout role: one block per batch chain =====
    const int b = bid;
    const int wv = tid >> 6, lane = tid & 63;
    const int jg = lane & 15, ir = lane >> 4;
    {
      unsigned pxx = Xst[b * 256 + tid];
      xh[0][tid] = (unsigned short)(pxx & 0xffffu);
      xl[0][tid] = (unsigned short)(pxx >> 16);
    }
    __syncthreads();
    int cur = 0;
    for (int tt = 0; tt < tnr; ++tt) {
      const int t = t0r + tt;
      const size_t rb = ((size_t)tt * NB + b) * (NS * NS);
      uint4v xhv[2], xlv[2];
      xhv[0] = *(const uint4v*)(&xh[cur][jg * 16]);
      xhv[1] = *(const uint4v*)(&xh[cur][jg * 16 + 8]);
      xlv[0] = *(const uint4v*)(&xl[cur][jg * 16]);
      xlv[1] = *(const uint4v*)(&xl[cur][jg * 16 + 8]);
      float d[16];
#pragma unroll 4
      for (int k = 0; k < 16; ++k) {
        const int i = wv * 64 + ir * 16 + k;
        const size_t ro = rb + (size_t)i * NS + jg * 16;
        uint4v a0 = *(const uint4v*)(Arh + ro);
        uint4v a1 = *(const uint4v*)(Arh + ro + 8);
        uint4v c0 = *(const uint4v*)(Arl + ro);
        uint4v c1 = *(const uint4v*)(Arl + ro + 8);
        float s1 = 0.f, s2 = 0.f;
#pragma unroll
        for (int p = 0; p < 4; ++p) {
          s1 = fdot2f(as_h2(a0[p]), as_h2(xhv[0][p]), s1);
          s2 = fdot2f(as_h2(a0[p]), as_h2(xlv[0][p]), s2);
          s2 = fdot2f(as_h2(c0[p]), as_h2(xhv[0][p]), s2);
          s1 = fdot2f(as_h2(a1[p]), as_h2(xhv[1][p]), s1);
          s2 = fdot2f(as_h2(a1[p]), as_h2(xlv[1][p]), s2);
          s2 = fdot2f(as_h2(c1[p]), as_h2(xhv[1][p]), s2);
        }
        d[k] = s1 + s2 * LO_INV;
      }
#pragma unroll
      for (int s = 1; s < 16; s <<= 1)
#pragma unroll
        for (int k = 0; k < 16; ++k) d[k] += __shfl_xor(d[k], s);
      if (jg == 0) {
        const int i0r = wv * 64 + ir * 16;
#pragma unroll
        for (int k4 = 0; k4 < 4; ++k4) {
          float4v vv = *(const float4v*)(V + ((size_t)t * NB + b) * NS + i0r + k4 * 4);
          float4v xn;
#pragma unroll
          for (int r = 0; r < 4; ++r) xn[r] = d[k4 * 4 + r] + vv[r];
          *(float4v*)(out + ((size_t)b * NT + t) * NS + i0r + k4 * 4) = xn;
#pragma unroll
          for (int r = 0; r < 4; ++r) {
            unsigned short hs, ls;
            split_hl(xn[r], hs, ls);
            xh[cur ^ 1][i0r + k4 * 4 + r] = hs;
            xl[cur ^ 1][i0r + k4 * 4 + r] = ls;
          }
        }
      }
      __syncthreads();
      cur ^= 1;
    }
    {
      unsigned pxx = (unsigned)xh[cur][tid] | ((unsigned)xl[cur][tid] << 16);
      Xst[b * 256 + tid] = pxx;
    }
  } else {
    // ===== A-materialization role (next chunk) =====
    const int pb = bid - nroll;
    const int wv = tid >> 6, lane = tid & 63;
    const int l15 = lane & 15, quad = lane >> 4;
    const int cb = (pb & 255) << 8;
    const int rt = pb >> 8;
    const int r0 = rt * 64 + wv * 16;       // chunk-local tb row base
    half8 Lh2[2], Ll2[2];
    const size_t lb = ((size_t)t0p * NB + r0 + l15) * NG + quad * 8;
#pragma unroll
    for (int kk = 0; kk < 2; ++kk) {
      Lh2[kk] = *(const half8*)(Lph + lb + kk * 32);
      Ll2[kk] = *(const half8*)(Lpl + lb + kk * 32);
    }
    float4v accA[16], accC[16];
#pragma unroll
    for (int cf = 0; cf < 16; ++cf) {
      accA[cf] = (float4v){0.f, 0.f, 0.f, 0.f};
      accC[cf] = (float4v){0.f, 0.f, 0.f, 0.f};
    }
#pragma unroll
    for (int cf = 0; cf < 16; ++cf) {
      const size_t mb = (size_t)(cb + cf * 16 + l15) * NG + quad * 8;
#pragma unroll
      for (int kk = 0; kk < 2; ++kk) {
        half8 Bh = *(const half8*)(MGh + mb + kk * 32);
        half8 Bl = *(const half8*)(MGl + mb + kk * 32);
        accA[cf] = __builtin_amdgcn_mfma_f32_16x16x32_f16(Lh2[kk], Bh, accA[cf], 0, 0, 0);
        accC[cf] = __builtin_amdgcn_mfma_f32_16x16x32_f16(Lh2[kk], Bl, accC[cf], 0, 0, 0);
        accC[cf] = __builtin_amdgcn_mfma_f32_16x16x32_f16(Ll2[kk], Bh, accC[cf], 0, 0, 0);
      }
    }
#pragma unroll
    for (int cf = 0; cf < 16; ++cf) {
      const int mloc = cb + cf * 16 + l15;
      const float b2 = b2a[mloc];
#pragma unroll
      for (int r = 0; r < 4; ++r) {
        float v = accA[cf][r] + accC[cf][r] * LO_INV + b2;
        unsigned short hs, ls;
        split_hl(v, hs, ls);
        const size_t gb = (size_t)(r0 + quad * 4 + r) * (NS * NS) + mloc;
        Awh[gb] = hs;
        Awl[gb] = ls;
      }
    }
  }
}

// ---------------- launch ----------------

static inline int imin(int a, int b) { return a < b ? a : b; }

extern "C" void kernel_launch(void* const* d_in, const int* in_sizes, int n_in,
                              void* d_out, int out_size, void* d_ws, size_t ws_size,
                              hipStream_t stream) {
  const float* x0  = (const float*)d_in[0];
  const float* ctx = (const float*)d_in[1];
  const float* usin = (const float*)d_in[2];
  const float* W1a = (const float*)d_in[3];
  const float* b1a = (const float*)d_in[4];
  const float* W2a = (const float*)d_in[5];
  const float* b2a = (const float*)d_in[6];
  const float* W1b = (const float*)d_in[7];
  const float* b1b = (const float*)d_in[8];
  const float* W2b = (const float*)d_in[9];
  const float* b2b = (const float*)d_in[10];
  float* out = (float*)d_out;

  const size_t perT  = (size_t)NB * NS * NS * 2;     //  8,388,608 (one array, per t)
  const size_t szMG1 = (size_t)NS * NS * NG * 2;     //  8,388,608 each
  const size_t szMBT = (size_t)NS * NG * NA * 2;     //  2,097,152 each
  const size_t szLp1 = (size_t)NT * NB * NG * 2;     //    409,600 each
  const size_t szLf  = (size_t)NT * NB * NG * 4;     //    819,200
  const size_t szGt  = (size_t)NH * NG * 4;          //     65,536 each
  const size_t szUp1 = (size_t)NT * NB * NG * NA * 2;// 26,214,400 each
  const size_t szV   = (size_t)NT * NB * NS * 4;     //  3,276,800
  const size_t szXst = (size_t)NB * NS * 4;          //     65,536

  const size_t fixed = 2 * szMG1 + 2 * szMBT + 2 * szLp1 + szLf + 2 * szGt +
                       2 * szUp1 + szV + szXst;

  size_t avail = (ws_size > fixed) ? (ws_size - fixed) : 0;
  bool dbuf = true;
  int Tc = (int)(avail / (4 * perT));
  if (Tc > 7) Tc = 7;
  if (Tc < 1) {
    dbuf = false;
    Tc = (int)(avail / (2 * perT));
    if (Tc > 13) Tc = 13;
    if (Tc < 1) Tc = 1;
  }

  char* p = (char*)d_ws;
  unsigned short* A0h = (unsigned short*)p; p += (size_t)Tc * perT;
  unsigned short* A0l = (unsigned short*)p; p += (size_t)Tc * perT;
  unsigned short* A1h = A0h; unsigned short* A1l = A0l;
  if (dbuf) {
    A1h = (unsigned short*)p; p += (size_t)Tc * perT;
    A1l = (unsigned short*)p; p += (size_t)Tc * perT;
  }
  unsigned short* MGh = (unsigned short*)p; p += szMG1;
  unsigned short* MGl = (unsigned short*)p; p += szMG1;
  unsigned short* MBTh = (unsigned short*)p; p += szMBT;
  unsigned short* MBTl = (unsigned short*)p; p += szMBT;
  unsigned short* Lph = (unsigned short*)p; p += szLp1;
  unsigned short* Lpl = (unsigned short*)p; p += szLp1;
  float* Lf  = (float*)p; p += szLf;
  float* Gt  = (float*)p; p += szGt;
  float* Gbt = (float*)p; p += szGt;
  unsigned short* Uph = (unsigned short*)p; p += szUp1;
  unsigned short* Upl = (unsigned short*)p; p += szUp1;
  float* Vg  = (float*)p; p += szV;
  unsigned* Xst = (unsigned*)p;

  // prep (all fully parallel, no Y/atomic-flag machinery)
  k_g<<<NG, NH, 0, stream>>>(W1a, b1a, W1b, b1b, Gt, Gbt);
  k_lag<<<(NT * NB + 255) / 256, 256, 0, stream>>>(ctx, Lf, Lph, Lpl);
  k_v<<<NT * NB, NS, 0, stream>>>(b2b, usin, Vg);
  k_mg<<<NS * NS / 256, 256, 0, stream>>>(W2a, Gt, MGh, MGl);
  k_mb<<<NS * NA / 256, 256, 0, stream>>>(W2b, Gbt, MBTh, MBTl);
  k_up<<<NT * NB, 256, 0, stream>>>(Lf, usin, Uph, Upl);
  k_x0<<<NB, 256, 0, stream>>>(x0, Xst);
  k_bu2<<<(NT * NB / 64) * 4, 256, 0, stream>>>(Uph, Upl, MBTh, MBTl, Vg);

  void* noargs;
  (void)noargs; (void)in_sizes; (void)n_in; (void)out_size;

  const int nc = (NT + Tc - 1) / Tc;
  if (dbuf) {
    // pipelined: launch L runs roll(chunk L-1) || pre(chunk L)
    for (int L = 0; L <= nc; ++L) {
      const int rc = L - 1, pc = L;
      const int nroll = (rc >= 0) ? NB : 0;
      const int t0r = (rc >= 0) ? rc * Tc : 0;
      const int tnr = (rc >= 0) ? imin(Tc, NT - t0r) : 0;
      const int t0p = (pc < nc) ? pc * Tc : 0;
      const int tnp = (pc < nc) ? imin(Tc, NT - t0p) : 0;
      const int grid = nroll + tnp * 256;
      const unsigned short* Arh = ((rc & 1) ? A1h : A0h);
      const unsigned short* Arl = ((rc & 1) ? A1l : A0l);
      unsigned short* Awh = ((pc & 1) ? A1h : A0h);
      unsigned short* Awl = ((pc & 1) ? A1l : A0l);
      k_pr<<<grid, 256, 0, stream>>>(Arh, Arl, Awh, Awl, Lph, Lpl, MGh, MGl,
                                     b2a, Vg, Xst, out, nroll, t0r, tnr, t0p);
    }
  } else {
    // sequential fallback on a single buffer
    for (int c = 0; c < nc; ++c) {
      const int t0 = c * Tc, tn = imin(Tc, NT - t0);
      k_pr<<<tn * 256, 256, 0, stream>>>(A0h, A0l, A0h, A0l, Lph, Lpl, MGh, MGl,
                                         b2a, Vg, Xst, out, 0, 0, 0, t0);
      k_pr<<<NB, 256, 0, stream>>>(A0h, A0l, A0h, A0l, Lph, Lpl, MGh, MGl,
                                   b2a, Vg, Xst, out, NB, t0, tn, 0);
    }
  }
}